// Round 3
// baseline (206.739 us; speedup 1.0000x reference)
//
#include <hip/hip_runtime.h>
#include <math.h>

// x: (B=32, C=3, H=512, W=512) fp32; affine warp, bilinear, zero pad.
constexpr int B = 32;
constexpr int C = 3;
constexpr int H = 512;
constexpr int W = 512;
constexpr int HW = H * W;

// ---------------------------------------------------------------------------
// overall = fw^-1 * diag(1/l1,1/l2,1) * fw reduces to a pure 2x2 linear map:
//   t00 = a c^2 + d s^2, t01 = t10 = c s (d-a), t11 = a s^2 + d c^2
// (a=1/l1, d=1/l2, c=cos(-th), s=sin(-th); translation cancels exactly).
//
// Mapping: block = 256 threads = 4 waves; waves (0,1)->row h px[0:256|256:512],
// waves (2,3)->row h+1. Each thread: 4 px strided by 64 lanes (adjacent lanes
// sample source points t00 px apart -> within-instruction line coalescing).
//
// Latency strategy: ALL 24 gathers per thread are unconditional (clamped
// addresses) and batched before any consumption -> ~12KB outstanding per
// wave, covers HBM latency. Validity masks + edge-select are folded into the
// 4 per-pixel slot WEIGHTS (computed once, shared across channels), so the
// load->use chain is just FMAs. Fully-OOB waves skip loads (__any).
// Output stores are nontemporal (never re-read; keep L2 for gathers).
// ---------------------------------------------------------------------------
__global__ __launch_bounds__(256)
void warp_kernel(const float* __restrict__ x,
                 const float* __restrict__ thetas,
                 const float* __restrict__ l1s,
                 const float* __restrict__ l2s,
                 float* __restrict__ out) {
    const int b = blockIdx.y;

    __shared__ float sc[4];
    if (threadIdx.x == 0) {
        double th = -(double)thetas[b];
        double c = cos(th), s = sin(th);
        double a = 1.0 / (double)l1s[b];
        double d = 1.0 / (double)l2s[b];
        sc[0] = (float)(a * c * c + d * s * s);
        sc[1] = (float)(c * s * (d - a));
        sc[2] = sc[1];
        sc[3] = (float)(a * s * s + d * c * c);
    }
    __syncthreads();
    const float t00 = sc[0], t01 = sc[1], t10 = sc[2], t11 = sc[3];

    const int tid   = threadIdx.x;
    const int lane  = tid & 63;
    const int wv    = tid >> 6;
    const int h     = (blockIdx.x << 1) | (wv >> 1);
    const int wbase = (wv & 1) << 8;

    const float Y = ((float)h + 0.5f) * (2.0f / (float)H) - 1.0f;

    int   off0[4], off1[4];
    float sw0[4], sw1[4], sw2[4], sw3[4];   // slot weights: row0.x/.y, row1.x/.y
    bool  any_valid = false;

    #pragma unroll
    for (int j = 0; j < 4; ++j) {
        const int w = wbase + (j << 6) + lane;
        const float X = ((float)w + 0.5f) * (2.0f / (float)W) - 1.0f;
        const float gx = (t00 * X + t01 * Y + 1.0f) * ((float)W * 0.5f) - 0.5f;
        const float gy = (t10 * X + t11 * Y + 1.0f) * ((float)H * 0.5f) - 0.5f;

        const float x0f = floorf(gx), y0f = floorf(gy);
        const float wx1 = gx - x0f, wx0 = 1.0f - wx1;
        const float wy1 = gy - y0f, wy0 = 1.0f - wy1;

        const int x0 = (int)x0f, y0 = (int)y0f;
        const int x1 = x0 + 1,  y1 = y0 + 1;

        const bool vx0 = ((unsigned)x0 < (unsigned)W);
        const bool vx1 = ((unsigned)x1 < (unsigned)W);
        const bool vy0 = ((unsigned)y0 < (unsigned)H);
        const bool vy1 = ((unsigned)y1 < (unsigned)H);
        any_valid = any_valid || ((vy0 || vy1) && (vx0 || vx1));

        const int xb  = min(max(x0, 0), W - 2);      // slot0=p[xb], slot1=p[xb+1]
        const bool xeq = (x0 == xb);
        off0[j] = min(max(y0, 0), H - 1) * W + xb;
        off1[j] = min(max(y1, 0), H - 1) * W + xb;

        // masked bilinear weights (0/1 masks as float multiplies)
        const float m00 = (vy0 && vx0) ? 1.0f : 0.0f;
        const float m01 = (vy0 && vx1) ? 1.0f : 0.0f;
        const float m10 = (vy1 && vx0) ? 1.0f : 0.0f;
        const float m11 = (vy1 && vx1) ? 1.0f : 0.0f;
        const float w00 = wy0 * wx0 * m00, w01 = wy0 * wx1 * m01;
        const float w10 = wy1 * wx0 * m10, w11 = wy1 * wx1 * m11;

        // fold the edge-select into the slot weights (shared by all channels):
        // xeq: slot0 holds x0, slot1 holds x1; else (x0 off-edge) swapped, and
        // the weight of the phantom slot is already 0 via its mask.
        sw0[j] = xeq ? w00 : w01;
        sw1[j] = xeq ? w01 : w00;
        sw2[j] = xeq ? w10 : w11;
        sw3[j] = xeq ? w11 : w10;
    }

    float r[C][4];
    #pragma unroll
    for (int ch = 0; ch < C; ++ch)
        #pragma unroll
        for (int j = 0; j < 4; ++j) r[ch][j] = 0.0f;

    if (__any(any_valid)) {
        const float* __restrict__ base = x + (size_t)b * C * HW;
        float2 v0[4][C], v1[4][C];
        // --- batch all 24 gathers, no consumers in between ---
        #pragma unroll
        for (int j = 0; j < 4; ++j) {
            #pragma unroll
            for (int ch = 0; ch < C; ++ch) {
                const float* __restrict__ p = base + ch * HW;
                v0[j][ch] = *reinterpret_cast<const float2*>(p + off0[j]);
                v1[j][ch] = *reinterpret_cast<const float2*>(p + off1[j]);
            }
        }
        // --- consume ---
        #pragma unroll
        for (int j = 0; j < 4; ++j) {
            #pragma unroll
            for (int ch = 0; ch < C; ++ch) {
                r[ch][j] = v0[j][ch].x * sw0[j] + v0[j][ch].y * sw1[j]
                         + v1[j][ch].x * sw2[j] + v1[j][ch].y * sw3[j];
            }
        }
    }

    const size_t obase = (size_t)b * C * HW + (size_t)h * W + (size_t)wbase + lane;
    #pragma unroll
    for (int ch = 0; ch < C; ++ch) {
        #pragma unroll
        for (int j = 0; j < 4; ++j) {
            __builtin_nontemporal_store(r[ch][j], out + obase + (size_t)ch * HW + (j << 6));
        }
    }
}

extern "C" void kernel_launch(void* const* d_in, const int* in_sizes, int n_in,
                              void* d_out, int out_size, void* d_ws, size_t ws_size,
                              hipStream_t stream) {
    const float* x      = (const float*)d_in[0];
    const float* thetas = (const float*)d_in[1];
    const float* l1s    = (const float*)d_in[2];
    const float* l2s    = (const float*)d_in[3];
    float* out          = (float*)d_out;

    warp_kernel<<<dim3(H / 2, B), 256, 0, stream>>>(x, thetas, l1s, l2s, out);
}

// Round 4
// 202.501 us; speedup vs baseline: 1.0209x; 1.0209x over previous
//
#include <hip/hip_runtime.h>
#include <math.h>

// x: (B=32, C=3, H=512, W=512) fp32; affine warp, bilinear, zero pad.
constexpr int B = 32;
constexpr int C = 3;
constexpr int H = 512;
constexpr int W = 512;
constexpr int HW = H * W;

// ---------------------------------------------------------------------------
// overall = fw^-1 * diag(1/l1,1/l2,1) * fw reduces to a pure 2x2 linear map:
//   t00 = a c^2 + d s^2, t01 = t10 = c s (d-a), t11 = a s^2 + d c^2
// (a=1/l1, d=1/l2, c=cos(-th), s=sin(-th); translation cancels exactly).
//
// Mapping: block = 256 threads = 4 waves; waves (0,1)->row h px[0:256|256:512],
// waves (2,3)->row h+1. Each thread: 4 px strided by 64 lanes (adjacent lanes
// sample source points ~t00 px apart -> line coalescing when t00 small).
//
// Bottleneck model (R1/R2 evidence): gather L1-transaction + latency bound.
// Strategy:
//  * PER-LANE predication on every gather (thread-level if + per-row if):
//    masked lanes issue NO L1 transactions (R2 showed dropping this costs
//    +24MB FETCH and +22us).
//  * All 24 predicated float2 gathers issued back-to-back BEFORE any
//    consumption -> ~12KB outstanding per wave covers HBM latency.
//  * Validity masks + x-edge-select folded into per-pixel slot weights
//    (shared across channels) -> load->use chain is pure FMA.
// ---------------------------------------------------------------------------
__global__ __launch_bounds__(256)
void warp_kernel(const float* __restrict__ x,
                 const float* __restrict__ thetas,
                 const float* __restrict__ l1s,
                 const float* __restrict__ l2s,
                 float* __restrict__ out) {
    const int b = blockIdx.y;

    __shared__ float sc[4];
    if (threadIdx.x == 0) {
        double th = -(double)thetas[b];
        double c = cos(th), s = sin(th);
        double a = 1.0 / (double)l1s[b];
        double d = 1.0 / (double)l2s[b];
        sc[0] = (float)(a * c * c + d * s * s);
        sc[1] = (float)(c * s * (d - a));
        sc[2] = sc[1];
        sc[3] = (float)(a * s * s + d * c * c);
    }
    __syncthreads();
    const float t00 = sc[0], t01 = sc[1], t10 = sc[2], t11 = sc[3];

    const int tid   = threadIdx.x;
    const int lane  = tid & 63;
    const int wv    = tid >> 6;
    const int h     = (blockIdx.x << 1) | (wv >> 1);
    const int wbase = (wv & 1) << 8;

    const float Y = ((float)h + 0.5f) * (2.0f / (float)H) - 1.0f;

    int   off0[4], off1[4];
    bool  pr0[4], pr1[4];
    float sw0[4], sw1[4], sw2[4], sw3[4];   // slot weights: row0.x/.y, row1.x/.y
    bool  any_valid = false;

    #pragma unroll
    for (int j = 0; j < 4; ++j) {
        const int w = wbase + (j << 6) + lane;
        const float X = ((float)w + 0.5f) * (2.0f / (float)W) - 1.0f;
        const float gx = (t00 * X + t01 * Y + 1.0f) * ((float)W * 0.5f) - 0.5f;
        const float gy = (t10 * X + t11 * Y + 1.0f) * ((float)H * 0.5f) - 0.5f;

        const float x0f = floorf(gx), y0f = floorf(gy);
        const float wx1 = gx - x0f, wx0 = 1.0f - wx1;
        const float wy1 = gy - y0f, wy0 = 1.0f - wy1;

        const int x0 = (int)x0f, y0 = (int)y0f;
        const int x1 = x0 + 1,  y1 = y0 + 1;

        const bool vx0 = ((unsigned)x0 < (unsigned)W);
        const bool vx1 = ((unsigned)x1 < (unsigned)W);
        const bool vy0 = ((unsigned)y0 < (unsigned)H);
        const bool vy1 = ((unsigned)y1 < (unsigned)H);

        const bool anyx = vx0 || vx1;
        pr0[j] = vy0 && anyx;
        pr1[j] = vy1 && anyx;
        any_valid = any_valid || pr0[j] || pr1[j];

        const int xb  = min(max(x0, 0), W - 2);      // slot0=p[xb], slot1=p[xb+1]
        const bool xeq = (x0 == xb);
        off0[j] = min(max(y0, 0), H - 1) * W + xb;
        off1[j] = min(max(y1, 0), H - 1) * W + xb;

        // masked bilinear weights (0/1 masks as float multiplies)
        const float m00 = (vy0 && vx0) ? 1.0f : 0.0f;
        const float m01 = (vy0 && vx1) ? 1.0f : 0.0f;
        const float m10 = (vy1 && vx0) ? 1.0f : 0.0f;
        const float m11 = (vy1 && vx1) ? 1.0f : 0.0f;
        const float w00 = wy0 * wx0 * m00, w01 = wy0 * wx1 * m01;
        const float w10 = wy1 * wx0 * m10, w11 = wy1 * wx1 * m11;

        // fold the x-edge-select into the slot weights (shared by channels)
        sw0[j] = xeq ? w00 : w01;
        sw1[j] = xeq ? w01 : w00;
        sw2[j] = xeq ? w10 : w11;
        sw3[j] = xeq ? w11 : w10;
    }

    float r[C][4];
    #pragma unroll
    for (int ch = 0; ch < C; ++ch)
        #pragma unroll
        for (int j = 0; j < 4; ++j) r[ch][j] = 0.0f;

    if (any_valid) {   // thread-level: OOB lanes exec-masked out of ALL loads
        const float* __restrict__ base = x + (size_t)b * C * HW;
        float2 v0[4][C], v1[4][C];
        #pragma unroll
        for (int j = 0; j < 4; ++j)
            #pragma unroll
            for (int ch = 0; ch < C; ++ch) {
                v0[j][ch] = make_float2(0.0f, 0.0f);
                v1[j][ch] = make_float2(0.0f, 0.0f);
            }
        // --- issue all 24 predicated gathers back-to-back ---
        #pragma unroll
        for (int j = 0; j < 4; ++j) {
            #pragma unroll
            for (int ch = 0; ch < C; ++ch) {
                const float* __restrict__ p = base + ch * HW;
                if (pr0[j]) v0[j][ch] = *reinterpret_cast<const float2*>(p + off0[j]);
                if (pr1[j]) v1[j][ch] = *reinterpret_cast<const float2*>(p + off1[j]);
            }
        }
        // --- consume ---
        #pragma unroll
        for (int j = 0; j < 4; ++j) {
            #pragma unroll
            for (int ch = 0; ch < C; ++ch) {
                r[ch][j] = v0[j][ch].x * sw0[j] + v0[j][ch].y * sw1[j]
                         + v1[j][ch].x * sw2[j] + v1[j][ch].y * sw3[j];
            }
        }
    }

    const size_t obase = (size_t)b * C * HW + (size_t)h * W + (size_t)wbase + lane;
    #pragma unroll
    for (int ch = 0; ch < C; ++ch) {
        #pragma unroll
        for (int j = 0; j < 4; ++j) {
            out[obase + (size_t)ch * HW + (j << 6)] = r[ch][j];
        }
    }
}

extern "C" void kernel_launch(void* const* d_in, const int* in_sizes, int n_in,
                              void* d_out, int out_size, void* d_ws, size_t ws_size,
                              hipStream_t stream) {
    const float* x      = (const float*)d_in[0];
    const float* thetas = (const float*)d_in[1];
    const float* l1s    = (const float*)d_in[2];
    const float* l2s    = (const float*)d_in[3];
    float* out          = (float*)d_out;

    warp_kernel<<<dim3(H / 2, B), 256, 0, stream>>>(x, thetas, l1s, l2s, out);
}

// Round 5
// 197.146 us; speedup vs baseline: 1.0487x; 1.0272x over previous
//
#include <hip/hip_runtime.h>
#include <math.h>

// x: (B=32, C=3, H=512, W=512) fp32; affine warp, bilinear, zero pad.
constexpr int B = 32;
constexpr int C = 3;
constexpr int H = 512;
constexpr int W = 512;
constexpr int HW = H * W;

typedef unsigned int v2u __attribute__((ext_vector_type(2)));
typedef float        v2f __attribute__((ext_vector_type(2)));

// Raw buffer load (8B). OOB (voffset+8 > num_records, incl. negative voffset
// viewed as huge unsigned) returns 0 with NO memory transaction — this is the
// hardware replacement for per-lane exec-mask predication.
static __device__ __forceinline__ v2f bload2(__amdgpu_buffer_rsrc_t r, int voff) {
    v2u u = __builtin_amdgcn_raw_buffer_load_b64(r, voff, 0, 0);
    return __builtin_bit_cast(v2f, u);
}

// ---------------------------------------------------------------------------
// overall = fw^-1 * diag(1/l1,1/l2,1) * fw reduces to a pure 2x2 linear map:
//   t00 = a c^2 + d s^2, t01 = t10 = c s (d-a), t11 = a s^2 + d c^2
// (a=1/l1, d=1/l2, c=cos(-th), s=sin(-th); translation cancels exactly).
//
// R1-R3 evidence: kernel is MLP-bound (VGPR 40-44 => ~3 loads in flight/wave
// => ~2.5KB/CU outstanding => ~3 TB/s). Fix: branch-free buffer loads with
// HARDWARE bounds checking:
//  * one SRD per (b,ch) plane, num_records = HW*4 bytes;
//  * y is NOT clamped — OOB rows produce OOB byte offsets -> hw returns 0,
//    zero L1/HBM traffic (keeps R1's FETCH, R2's straight-line code);
//  * lanes with both x-taps invalid force voffset=-1 (OOB);
//  * x-edge select + validity masks folded into per-pixel slot weights;
//  * all 24 loads issued back-to-back, no branches -> memory clause;
//    __launch_bounds__(256,4) gives the allocator room (<=128 VGPR) to keep
//    all destinations live.
// ---------------------------------------------------------------------------
__global__ __launch_bounds__(256, 4)
void warp_kernel(const float* __restrict__ x,
                 const float* __restrict__ thetas,
                 const float* __restrict__ l1s,
                 const float* __restrict__ l2s,
                 float* __restrict__ out) {
    const int b = blockIdx.y;

    __shared__ float sc[4];
    if (threadIdx.x == 0) {
        double th = -(double)thetas[b];
        double c = cos(th), s = sin(th);
        double a = 1.0 / (double)l1s[b];
        double d = 1.0 / (double)l2s[b];
        sc[0] = (float)(a * c * c + d * s * s);
        sc[1] = (float)(c * s * (d - a));
        sc[2] = sc[1];
        sc[3] = (float)(a * s * s + d * c * c);
    }
    __syncthreads();
    const float t00 = sc[0], t01 = sc[1], t10 = sc[2], t11 = sc[3];

    const int tid   = threadIdx.x;
    const int lane  = tid & 63;
    const int wv    = tid >> 6;
    const int h     = (blockIdx.x << 1) | (wv >> 1);
    const int wbase = (wv & 1) << 8;

    const float Y = ((float)h + 0.5f) * (2.0f / (float)H) - 1.0f;

    // One SRD per channel plane of this batch (base is block-uniform -> SGPRs).
    __amdgpu_buffer_rsrc_t rs[C];
    #pragma unroll
    for (int ch = 0; ch < C; ++ch) {
        rs[ch] = __builtin_amdgcn_make_buffer_rsrc(
            (void*)(x + (size_t)(b * C + ch) * HW), (short)0, HW * 4, 0x00020000);
    }

    int   voff0[4], voff1[4];
    float sw0[4], sw1[4], sw2[4], sw3[4];   // slot weights: row0.x/.y, row1.x/.y

    #pragma unroll
    for (int j = 0; j < 4; ++j) {
        const int w = wbase + (j << 6) + lane;
        const float X = ((float)w + 0.5f) * (2.0f / (float)W) - 1.0f;
        const float gx = (t00 * X + t01 * Y + 1.0f) * ((float)W * 0.5f) - 0.5f;
        const float gy = (t10 * X + t11 * Y + 1.0f) * ((float)H * 0.5f) - 0.5f;

        const float x0f = floorf(gx), y0f = floorf(gy);
        const float wx1 = gx - x0f, wx0 = 1.0f - wx1;
        const float wy1 = gy - y0f, wy0 = 1.0f - wy1;

        const int x0 = (int)x0f, y0 = (int)y0f;
        const int x1 = x0 + 1,  y1 = y0 + 1;

        const bool vx0 = ((unsigned)x0 < (unsigned)W);
        const bool vx1 = ((unsigned)x1 < (unsigned)W);
        const bool vy0 = ((unsigned)y0 < (unsigned)H);
        const bool vy1 = ((unsigned)y1 < (unsigned)H);
        const bool anyx = vx0 || vx1;

        const int xb   = min(max(x0, 0), W - 2);   // slot0=p[xb], slot1=p[xb+1]
        const bool xeq = (x0 == xb);

        // y clamped only to keep the byte offset in int range; [-1,H] preserves
        // OOB-ness (-1 -> negative offset, H -> >= num_records).
        const int yc0 = min(max(y0, -1), H);
        const int yc1 = min(max(y1, -1), H);
        voff0[j] = anyx ? (yc0 * W + xb) * 4 : -1;
        voff1[j] = anyx ? (yc1 * W + xb) * 4 : -1;

        const float m00 = (vy0 && vx0) ? 1.0f : 0.0f;
        const float m01 = (vy0 && vx1) ? 1.0f : 0.0f;
        const float m10 = (vy1 && vx0) ? 1.0f : 0.0f;
        const float m11 = (vy1 && vx1) ? 1.0f : 0.0f;
        const float w00 = wy0 * wx0 * m00, w01 = wy0 * wx1 * m01;
        const float w10 = wy1 * wx0 * m10, w11 = wy1 * wx1 * m11;

        sw0[j] = xeq ? w00 : w01;
        sw1[j] = xeq ? w01 : w00;
        sw2[j] = xeq ? w10 : w11;
        sw3[j] = xeq ? w11 : w10;
    }

    // --- all 24 gathers, branch-free, back-to-back ---
    v2f v0[4][C], v1[4][C];
    #pragma unroll
    for (int j = 0; j < 4; ++j) {
        #pragma unroll
        for (int ch = 0; ch < C; ++ch) {
            v0[j][ch] = bload2(rs[ch], voff0[j]);
            v1[j][ch] = bload2(rs[ch], voff1[j]);
        }
    }

    // --- consume ---
    float r[C][4];
    #pragma unroll
    for (int j = 0; j < 4; ++j) {
        #pragma unroll
        for (int ch = 0; ch < C; ++ch) {
            r[ch][j] = v0[j][ch].x * sw0[j] + v0[j][ch].y * sw1[j]
                     + v1[j][ch].x * sw2[j] + v1[j][ch].y * sw3[j];
        }
    }

    const size_t obase = (size_t)b * C * HW + (size_t)h * W + (size_t)wbase + lane;
    #pragma unroll
    for (int ch = 0; ch < C; ++ch) {
        #pragma unroll
        for (int j = 0; j < 4; ++j) {
            out[obase + (size_t)ch * HW + (j << 6)] = r[ch][j];
        }
    }
}

extern "C" void kernel_launch(void* const* d_in, const int* in_sizes, int n_in,
                              void* d_out, int out_size, void* d_ws, size_t ws_size,
                              hipStream_t stream) {
    const float* x      = (const float*)d_in[0];
    const float* thetas = (const float*)d_in[1];
    const float* l1s    = (const float*)d_in[2];
    const float* l2s    = (const float*)d_in[3];
    float* out          = (float*)d_out;

    warp_kernel<<<dim3(H / 2, B), 256, 0, stream>>>(x, thetas, l1s, l2s, out);
}

// Round 6
// 191.044 us; speedup vs baseline: 1.0822x; 1.0319x over previous
//
#include <hip/hip_runtime.h>
#include <math.h>

// x: (B=32, C=3, H=512, W=512) fp32; affine warp, bilinear, zero pad.
constexpr int B = 32;
constexpr int C = 3;
constexpr int H = 512;
constexpr int W = 512;
constexpr int HW = H * W;

typedef unsigned int v2u __attribute__((ext_vector_type(2)));
typedef float        v2f __attribute__((ext_vector_type(2)));

// Raw buffer load (8B). OOB voffset (negative => huge unsigned, or >= num
// records) returns 0 with NO memory transaction — hardware per-lane masking.
static __device__ __forceinline__ v2f bload2(__amdgpu_buffer_rsrc_t r, int voff) {
    v2u u = __builtin_amdgcn_raw_buffer_load_b64(r, voff, 0, 0);
    return __builtin_bit_cast(v2f, u);
}

// ---------------------------------------------------------------------------
// overall = fw^-1 * diag(1/l1,1/l2,1) * fw reduces to a pure 2x2 linear map:
//   t00 = a c^2 + d s^2, t01 = t10 = c s (d-a), t11 = a s^2 + d c^2
// (a=1/l1, d=1/l2, c=cos(-th), s=sin(-th); translation cancels exactly).
//
// R1-R4 matrix: interleaved load+consume (R1, 64us) beats batched (R3/R4,
// 77-78us) — the compiler register-minimizes batches into serialized
// vmcnt clusters, while interleaved code software-pipelines group k+1's
// loads against group k's FMAs. Masking matters (R2 unmasked: +24MB FETCH,
// 86us); hw-OOB == sw-mask on traffic.
//
// R5 = the untested cell: INTERLEAVED structure + hw-OOB buffer loads.
//  * one SRD per (b,ch) plane, num_records = HW*4 bytes;
//  * y unclamped-in-spirit (clamped to [-1,H] only for int-range safety):
//    OOB rows/cols -> hw returns 0, zero traffic;
//  * fully-x-OOB lanes force voffset=-1;
//  * x-edge select + validity folded into per-pixel slot weights;
//  * thread-level any_valid skip for fully-OOB border lanes/waves.
// ---------------------------------------------------------------------------
__global__ __launch_bounds__(256)
void warp_kernel(const float* __restrict__ x,
                 const float* __restrict__ thetas,
                 const float* __restrict__ l1s,
                 const float* __restrict__ l2s,
                 float* __restrict__ out) {
    const int b = blockIdx.y;

    __shared__ float sc[4];
    if (threadIdx.x == 0) {
        double th = -(double)thetas[b];
        double c = cos(th), s = sin(th);
        double a = 1.0 / (double)l1s[b];
        double d = 1.0 / (double)l2s[b];
        sc[0] = (float)(a * c * c + d * s * s);
        sc[1] = (float)(c * s * (d - a));
        sc[2] = sc[1];
        sc[3] = (float)(a * s * s + d * c * c);
    }
    __syncthreads();
    const float t00 = sc[0], t01 = sc[1], t10 = sc[2], t11 = sc[3];

    const int tid   = threadIdx.x;
    const int lane  = tid & 63;
    const int wv    = tid >> 6;
    const int h     = (blockIdx.x << 1) | (wv >> 1);
    const int wbase = (wv & 1) << 8;

    const float Y = ((float)h + 0.5f) * (2.0f / (float)H) - 1.0f;

    // One SRD per channel plane of this batch (block-uniform -> SGPRs).
    __amdgpu_buffer_rsrc_t rs[C];
    #pragma unroll
    for (int ch = 0; ch < C; ++ch) {
        rs[ch] = __builtin_amdgcn_make_buffer_rsrc(
            (void*)(x + (size_t)(b * C + ch) * HW), (short)0, HW * 4, 0x00020000);
    }

    int   voff0[4], voff1[4];
    float sw0[4], sw1[4], sw2[4], sw3[4];   // slot weights: row0.x/.y, row1.x/.y
    bool  any_valid = false;

    #pragma unroll
    for (int j = 0; j < 4; ++j) {
        const int w = wbase + (j << 6) + lane;
        const float X = ((float)w + 0.5f) * (2.0f / (float)W) - 1.0f;
        const float gx = (t00 * X + t01 * Y + 1.0f) * ((float)W * 0.5f) - 0.5f;
        const float gy = (t10 * X + t11 * Y + 1.0f) * ((float)H * 0.5f) - 0.5f;

        const float x0f = floorf(gx), y0f = floorf(gy);
        const float wx1 = gx - x0f, wx0 = 1.0f - wx1;
        const float wy1 = gy - y0f, wy0 = 1.0f - wy1;

        const int x0 = (int)x0f, y0 = (int)y0f;
        const int x1 = x0 + 1,  y1 = y0 + 1;

        const bool vx0 = ((unsigned)x0 < (unsigned)W);
        const bool vx1 = ((unsigned)x1 < (unsigned)W);
        const bool vy0 = ((unsigned)y0 < (unsigned)H);
        const bool vy1 = ((unsigned)y1 < (unsigned)H);
        const bool anyx = vx0 || vx1;
        any_valid = any_valid || ((vy0 || vy1) && anyx);

        const int xb   = min(max(x0, 0), W - 2);   // slot0=p[xb], slot1=p[xb+1]
        const bool xeq = (x0 == xb);

        // y clamped to [-1,H] only to keep the byte offset in int range;
        // OOB-ness preserved (-1 -> negative voffset, H -> >= num_records).
        const int yc0 = min(max(y0, -1), H);
        const int yc1 = min(max(y1, -1), H);
        voff0[j] = anyx ? (yc0 * W + xb) * 4 : -1;
        voff1[j] = anyx ? (yc1 * W + xb) * 4 : -1;

        const float m00 = (vy0 && vx0) ? 1.0f : 0.0f;
        const float m01 = (vy0 && vx1) ? 1.0f : 0.0f;
        const float m10 = (vy1 && vx0) ? 1.0f : 0.0f;
        const float m11 = (vy1 && vx1) ? 1.0f : 0.0f;
        const float w00 = wy0 * wx0 * m00, w01 = wy0 * wx1 * m01;
        const float w10 = wy1 * wx0 * m10, w11 = wy1 * wx1 * m11;

        sw0[j] = xeq ? w00 : w01;
        sw1[j] = xeq ? w01 : w00;
        sw2[j] = xeq ? w10 : w11;
        sw3[j] = xeq ? w11 : w10;
    }

    float r[C][4];
    #pragma unroll
    for (int ch = 0; ch < C; ++ch)
        #pragma unroll
        for (int j = 0; j < 4; ++j) r[ch][j] = 0.0f;

    if (any_valid) {
        // Interleaved: load pair + consume per (j,ch) — the R1 shape the
        // compiler pipelines well; hw-OOB makes each group branch-free.
        #pragma unroll
        for (int j = 0; j < 4; ++j) {
            #pragma unroll
            for (int ch = 0; ch < C; ++ch) {
                const v2f v0 = bload2(rs[ch], voff0[j]);
                const v2f v1 = bload2(rs[ch], voff1[j]);
                r[ch][j] = v0.x * sw0[j] + v0.y * sw1[j]
                         + v1.x * sw2[j] + v1.y * sw3[j];
            }
        }
    }

    const size_t obase = (size_t)b * C * HW + (size_t)h * W + (size_t)wbase + lane;
    #pragma unroll
    for (int ch = 0; ch < C; ++ch) {
        #pragma unroll
        for (int j = 0; j < 4; ++j) {
            out[obase + (size_t)ch * HW + (j << 6)] = r[ch][j];
        }
    }
}

extern "C" void kernel_launch(void* const* d_in, const int* in_sizes, int n_in,
                              void* d_out, int out_size, void* d_ws, size_t ws_size,
                              hipStream_t stream) {
    const float* x      = (const float*)d_in[0];
    const float* thetas = (const float*)d_in[1];
    const float* l1s    = (const float*)d_in[2];
    const float* l2s    = (const float*)d_in[3];
    float* out          = (float*)d_out;

    warp_kernel<<<dim3(H / 2, B), 256, 0, stream>>>(x, thetas, l1s, l2s, out);
}